// Round 8
// baseline (419.404 us; speedup 1.0000x reference)
//
#include <hip/hip_runtime.h>

// CapsuleLayer dynamic routing, MI355X fp32.
// x: [B=64, N=2048, I=8], W: [J=32, N=2048, D=16, I=8], out v: [B=64, J=32, D=16]
//
// R13: kill the in-loop x scalar loads. R12 counters: phase dur pinned at
// 46.6us across occupancy 18->52%, BG 8->4, CHUNK 32->16, HBM 30->63MB; and
// phase0 (no barriers/softmax/DPP) == phase1 == 46.6us -> the common cost is
// the inner-loop LOAD PATH, not routing machinery. Per n the wave issues 4
// un-prefetched s_load_dwordx8 of x (L3 flushed by harness poison -> ~900cy
// HBM latency, cover only ~110 VALU cy; 900/110 > 8 co-waves). Fix: stage
// the block's x tile (BG x CHUNK x 8 = 2KB) into LDS ONCE at block start;
// in-loop x reads become uniform-address LDS broadcasts (conflict-free).
// In-loop global traffic is now W only (register double-buffer, proven
// codegen: VGPR 32, no spills). Everything else identical to R12 for a
// clean A/B: BG=4, grid 2048, launch_bounds(256,8), same XCD swizzle.

#define BB_ 64
#define NN_ 2048
#define II_ 8
#define JJ_ 32
#define DD_ 16
#define NCHUNKS 128
#define CHUNK 16       /* n's per block */
#define BG 4           /* b's per block */
#define NBG (BB_ / BG) /* 16 */
#define EPS_ 1e-7f

#define PARTIAL_FLOATS (NCHUNKS * BB_ * JJ_ * DD_) /* 4M floats = 16.8 MB */

typedef __attribute__((ext_vector_type(2))) float v2f;

// DPP helpers (VALU-pipe cross-lane). CTRL must be an immediate.
template <int CTRL>
__device__ __forceinline__ float dpp_add(float v) {
  const int s = __builtin_amdgcn_update_dpp(
      0, __builtin_bit_cast(int, v), CTRL, 0xf, 0xf, true);
  return v + __builtin_bit_cast(float, s);
}
#define DPP_QP_XOR1 0xB1      /* quad_perm [1,0,3,2]  : lane ^ 1 */
#define DPP_QP_XOR2 0x4E      /* quad_perm [2,3,0,1]  : lane ^ 2 */
#define DPP_HALF_MIRROR 0x141 /* mirror within 8      : lane ^ 7 */
#define DPP_ROR8 0x128        /* row_ror:8 (16-lane)  : lane ^ 8 */

struct W8 {
  v2f k[8];  // k[i] = {W[j][n][2p][i], W[j][n][2p+1][i]} -- pk operands
};

// Load 16 consecutive floats (d-pair {2p,2p+1}, all 8 i's) and pack into pk
// pairs immediately; raw float4 temps die here. Proven-clean codegen.
__device__ __forceinline__ W8 loadW(const float* p) {
  const float4* q = (const float4*)p;
  const float4 t0 = q[0], t1 = q[1], t2 = q[2], t3 = q[3];
  W8 w = {{{t0.x, t2.x}, {t0.y, t2.y},
           {t0.z, t2.z}, {t0.w, t2.w},
           {t1.x, t3.x}, {t1.y, t3.y},
           {t1.z, t3.z}, {t1.w, t3.w}}};
  return w;
}

// u[b] = {u_hat[b][j][n][2p], u_hat[b][j][n][2p+1]}; x sourced from the LDS
// tile (uniform address across the wave -> broadcast, no bank conflicts).
__device__ __forceinline__ void compute_u(const W8& w,
                                          const float (*xs)[CHUNK * II_],
                                          int nl, v2f (&u)[BG]) {
#pragma unroll
  for (int b = 0; b < BG; ++b) {
    const float4* xr = (const float4*)&xs[b][nl * II_];
    const float4 xa = xr[0];
    const float4 xb = xr[1];
    v2f acc = w.k[0] * xa.x;
    acc += w.k[1] * xa.y;
    acc += w.k[2] * xa.z;
    acc += w.k[3] * xa.w;
    acc += w.k[4] * xb.x;
    acc += w.k[5] * xb.y;
    acc += w.k[6] * xb.z;
    acc += w.k[7] * xb.w;
    u[b] = acc;
  }
}

// Phase kernel: 256 threads = (j = tid>>3) x (p = tid&7); thread owns output
// cap j, dims d in {2p,2p+1}, for 4 b's. blockIdx = bg*NCHUNKS + chunk so
// blockIdx%8 == chunk%8 -> all 16 blocks sharing a W chunk-slab (256 KB) land
// on one XCD (16 slabs x 256 KB = 4 MB = one L2).
template <int PHASE>
__global__ __launch_bounds__(256, 8) void caps_phase(
    const float* __restrict__ x, const float* __restrict__ W,
    const float* __restrict__ V, float* __restrict__ partial) {
  const int tid = threadIdx.x;
  const int j = tid >> 3;
  const int p = tid & 7;
  const int chunk = blockIdx.x & (NCHUNKS - 1);
  const int bg = blockIdx.x >> 7;
  const int b0 = bg * BG;
  const int n0 = chunk * CHUNK;

  __shared__ float lmat[BG][JJ_];
  __shared__ float cmat[BG][JJ_];
  __shared__ float xs[BG][CHUNK * II_];  // 4 x 128 floats = 2 KB

  // Stage the x tile ONCE: rows b0..b0+3, n0..n0+15, all 8 i. 4 contiguous
  // 512B segments; tid>>6 picks the row, (tid&63)*2 the float2 within it.
  {
    const int b = tid >> 6;
    const int f = (tid & 63) * 2;
    const float2 t =
        *(const float2*)&x[((size_t)(b0 + b) * NN_ + n0) * II_ + f];
    *(float2*)&xs[b][f] = t;
  }

  // W[j][n][d][i]: thread reads 16 consecutive floats at j*262144 + n*128 + p*16.
  const float* wp = W + (size_t)j * (NN_ * DD_ * II_) +
                    (size_t)n0 * (DD_ * II_) + (size_t)p * 16;

  // V fragment: V[b0+b][j][2p..2p+1] for 4 b's.
  float v0r[BG], v1r[BG];
  if (PHASE > 0) {
#pragma unroll
    for (int b = 0; b < BG; ++b) {
      const float2 vv =
          *(const float2*)&V[((size_t)(b0 + b) * JJ_ + j) * DD_ + 2 * p];
      v0r[b] = vv.x;
      v1r[b] = vv.y;
    }
  }

  v2f s[BG];
#pragma unroll
  for (int b = 0; b < BG; ++b) s[b] = (v2f)(0.f);

  W8 wc = loadW(wp);
  __syncthreads();  // xs ready (overlapped with first W load + V load)

  for (int nl = 0; nl < CHUNK; ++nl) {
    // Register double-buffer: prefetch next n's W while computing this one.
    const int nf = (nl + 1 < CHUNK) ? nl + 1 : nl;
    const W8 wn = loadW(wp + (size_t)nf * 128);

    v2f u[BG];
    compute_u(wc, xs, nl, u);

    if (PHASE == 0) {
      // softmax(0) over J is uniform -> plain sum (scale at store).
#pragma unroll
      for (int b = 0; b < BG; ++b) s[b] += u[b];
    } else {
      // logits l[b][j] = sum_d u_hat*V: 2-elem partial per lane, then xor
      // butterfly over the 8 p-lanes.
#pragma unroll
      for (int b = 0; b < BG; ++b) {
        float lp = u[b].x * v0r[b] + u[b].y * v1r[b];
        lp = dpp_add<DPP_QP_XOR1>(lp);
        lp = dpp_add<DPP_QP_XOR2>(lp);
        lp = dpp_add<DPP_HALF_MIRROR>(lp);
        if (p == 0) lmat[b][j] = lp;
      }
      __syncthreads();
      // softmax over j (32 entries) x 4 b; threads tid<128 handle 1 entry.
      // |logit| <= ~3: exp safe without max subtraction (validated R2/R4).
      if (tid < BG * JJ_) {
        const int jj = tid & 31;
        const int bb = tid >> 5;
        float e0 = __expf(lmat[bb][jj]);
        float m0 = e0;
        m0 = dpp_add<DPP_QP_XOR1>(m0);
        m0 = dpp_add<DPP_QP_XOR2>(m0);
        m0 = dpp_add<DPP_HALF_MIRROR>(m0);
        m0 = dpp_add<DPP_ROR8>(m0);
        m0 += __shfl_xor(m0, 16);
        cmat[bb][jj] = e0 * __builtin_amdgcn_rcpf(m0);
      }
      __syncthreads();
#pragma unroll
      for (int b = 0; b < BG; ++b) {
        const float c = cmat[b][j];  // broadcast (all p-lanes same addr)
        s[b] += u[b] * c;            // one v_pk_fma
      }
      // no 3rd sync needed: next iter writes lmat only after passing the
      // cmat barrier above; all cmat readers finish before that barrier.
    }
    wc = wn;
  }

  const float scale = (PHASE == 0) ? (1.0f / 32.0f) : 1.0f;
#pragma unroll
  for (int b = 0; b < BG; ++b) {
    const size_t off =
        ((size_t)chunk * BB_ + (b0 + b)) * (JJ_ * DD_) + j * DD_ + 2 * p;
    *(float2*)&partial[off] = make_float2(s[b].x * scale, s[b].y * scale);
  }
}

// Reduce over chunks + squash. MODE 0: V = v ; 1: V += v ; 2: out = v.
// 128 blocks x 256 threads, 1 elem/thread; unroll 16 keeps 16 loads in flight.
template <int MODE>
__global__ __launch_bounds__(256) void caps_reduce(
    const float* __restrict__ partial, float* __restrict__ V,
    float* __restrict__ out) {
  const int t = blockIdx.x * 256 + threadIdx.x;  // [0, B*J*D)
  float s = 0.f;
#pragma unroll 16
  for (int c = 0; c < NCHUNKS; ++c)
    s += partial[(size_t)c * (BB_ * JJ_ * DD_) + t];
  // sum of squares over d (16 consecutive lanes = one (b,j))
  float ss = s * s;
  ss += __shfl_xor(ss, 1);
  ss += __shfl_xor(ss, 2);
  ss += __shfl_xor(ss, 4);
  ss += __shfl_xor(ss, 8);
  const float v = s / sqrtf(ss + EPS_);
  if (MODE == 0)
    V[t] = v;
  else if (MODE == 1)
    V[t] += v;
  else
    out[t] = v;
}

extern "C" void kernel_launch(void* const* d_in, const int* in_sizes, int n_in,
                              void* d_out, int out_size, void* d_ws,
                              size_t ws_size, hipStream_t stream) {
  const float* x = (const float*)d_in[0];
  const float* W = (const float*)d_in[1];
  float* out = (float*)d_out;
  float* partial = (float*)d_ws;        // 16.8 MB
  float* V = partial + PARTIAL_FLOATS;  // 128 KB

  const dim3 kgrid(NBG * NCHUNKS);            // 2048 blocks x 256 threads
  const dim3 rgrid((BB_ * JJ_ * DD_) / 256);  // 128 blocks x 256 threads

  caps_phase<0><<<kgrid, 256, 0, stream>>>(x, W, nullptr, partial);
  caps_reduce<0><<<rgrid, 256, 0, stream>>>(partial, V, out);
  caps_phase<1><<<kgrid, 256, 0, stream>>>(x, W, V, partial);
  caps_reduce<1><<<rgrid, 256, 0, stream>>>(partial, V, out);
  caps_phase<2><<<kgrid, 256, 0, stream>>>(x, W, V, partial);
  caps_reduce<2><<<rgrid, 256, 0, stream>>>(partial, V, out);
}

// Round 9
// 187.743 us; speedup vs baseline: 2.2339x; 2.2339x over previous
//
#include <hip/hip_runtime.h>

// CapsuleLayer dynamic routing, MI355X fp32.
// x: [B=64, N=2048, I=8], W: [J=32, N=2048, D=16, I=8], out v: [B=64, J=32, D=16]
//
// R14: R13's x-in-LDS idea, with the register budget restored. R13's
// launch_bounds(256,8) capped VGPRs at 64; moving x from SGPRs to VGPRs
// overflowed that -> per-iter scratch spill (WRITE_SIZE 236MB vs 16.8MB
// partial), phases 154us HBM-bound on spill traffic. Fix: launch_bounds
// (256,4) (128 VGPR, live set ~110, no spill) + BG=8 (grid 1024, 4
// blocks/CU -- the proven R5 config family). x tile (8b x 16n x 8i = 4KB)
// staged into LDS once per block; in-loop x reads are wave-uniform LDS
// broadcasts (conflict-free). In-loop global traffic = W only (register
// dist-1 double-buffer, proven codegen). R12 showed phase0 == phase1 ==
// 46.6us across occupancy 18->52% -> memory path convicted; this removes
// the x half of it. If phases stay ~46us, W stream is convicted -> R15
// stages W via global_load_lds.

#define BB_ 64
#define NN_ 2048
#define II_ 8
#define JJ_ 32
#define DD_ 16
#define NCHUNKS 128
#define CHUNK 16       /* n's per block */
#define BG 8           /* b's per block */
#define NBG (BB_ / BG) /* 8 */
#define EPS_ 1e-7f

#define PARTIAL_FLOATS (NCHUNKS * BB_ * JJ_ * DD_) /* 4M floats = 16.8 MB */

typedef __attribute__((ext_vector_type(2))) float v2f;

// DPP helpers (VALU-pipe cross-lane). CTRL must be an immediate.
template <int CTRL>
__device__ __forceinline__ float dpp_add(float v) {
  const int s = __builtin_amdgcn_update_dpp(
      0, __builtin_bit_cast(int, v), CTRL, 0xf, 0xf, true);
  return v + __builtin_bit_cast(float, s);
}
#define DPP_QP_XOR1 0xB1      /* quad_perm [1,0,3,2]  : lane ^ 1 */
#define DPP_QP_XOR2 0x4E      /* quad_perm [2,3,0,1]  : lane ^ 2 */
#define DPP_HALF_MIRROR 0x141 /* mirror within 8      : lane ^ 7 */
#define DPP_ROR8 0x128        /* row_ror:8 (16-lane)  : lane ^ 8 */

struct W8 {
  v2f k[8];  // k[i] = {W[j][n][2p][i], W[j][n][2p+1][i]} -- pk operands
};

// Load 16 consecutive floats (d-pair {2p,2p+1}, all 8 i's) and pack into pk
// pairs immediately; raw float4 temps die here. Proven-clean codegen.
__device__ __forceinline__ W8 loadW(const float* p) {
  const float4* q = (const float4*)p;
  const float4 t0 = q[0], t1 = q[1], t2 = q[2], t3 = q[3];
  W8 w = {{{t0.x, t2.x}, {t0.y, t2.y},
           {t0.z, t2.z}, {t0.w, t2.w},
           {t1.x, t3.x}, {t1.y, t3.y},
           {t1.z, t3.z}, {t1.w, t3.w}}};
  return w;
}

// u[b] = {u_hat[b][j][n][2p], u_hat[b][j][n][2p+1]}; x sourced from the LDS
// tile (uniform address across the wave -> broadcast, no bank conflicts).
__device__ __forceinline__ void compute_u(const W8& w,
                                          const float (*xs)[CHUNK * II_],
                                          int nl, v2f (&u)[BG]) {
#pragma unroll
  for (int b = 0; b < BG; ++b) {
    const float4* xr = (const float4*)&xs[b][nl * II_];
    const float4 xa = xr[0];
    const float4 xb = xr[1];
    v2f acc = w.k[0] * xa.x;
    acc += w.k[1] * xa.y;
    acc += w.k[2] * xa.z;
    acc += w.k[3] * xa.w;
    acc += w.k[4] * xb.x;
    acc += w.k[5] * xb.y;
    acc += w.k[6] * xb.z;
    acc += w.k[7] * xb.w;
    u[b] = acc;
  }
}

// Phase kernel: 256 threads = (j = tid>>3) x (p = tid&7); thread owns output
// cap j, dims d in {2p,2p+1}, for 8 b's. blockIdx = bg*NCHUNKS + chunk so
// blockIdx%8 == chunk%8 -> all 8 blocks sharing a W chunk-slab (256 KB) land
// on one XCD (16 slabs x 256 KB = 4 MB = one L2).
template <int PHASE>
__global__ __launch_bounds__(256, 4) void caps_phase(
    const float* __restrict__ x, const float* __restrict__ W,
    const float* __restrict__ V, float* __restrict__ partial) {
  const int tid = threadIdx.x;
  const int j = tid >> 3;
  const int p = tid & 7;
  const int chunk = blockIdx.x & (NCHUNKS - 1);
  const int bg = blockIdx.x >> 7;
  const int b0 = bg * BG;
  const int n0 = chunk * CHUNK;

  __shared__ float lmat[BG][JJ_];
  __shared__ float cmat[BG][JJ_];
  __shared__ float xs[BG][CHUNK * II_];  // 8 x 128 floats = 4 KB

  // Stage the x tile ONCE: rows b0..b0+7, n0..n0+15, all 8 i. 8 contiguous
  // 512B segments; tid>>5 picks the row, (tid&31)*4 the float4 within it.
  {
    const int b = tid >> 5;
    const int f = (tid & 31) * 4;
    const float4 t =
        *(const float4*)&x[((size_t)(b0 + b) * NN_ + n0) * II_ + f];
    *(float4*)&xs[b][f] = t;
  }

  // W[j][n][d][i]: thread reads 16 consecutive floats at j*262144 + n*128 + p*16.
  const float* wp = W + (size_t)j * (NN_ * DD_ * II_) +
                    (size_t)n0 * (DD_ * II_) + (size_t)p * 16;

  // V fragment: V[b0+b][j][2p..2p+1] for 8 b's.
  float v0r[BG], v1r[BG];
  if (PHASE > 0) {
#pragma unroll
    for (int b = 0; b < BG; ++b) {
      const float2 vv =
          *(const float2*)&V[((size_t)(b0 + b) * JJ_ + j) * DD_ + 2 * p];
      v0r[b] = vv.x;
      v1r[b] = vv.y;
    }
  }

  v2f s[BG];
#pragma unroll
  for (int b = 0; b < BG; ++b) s[b] = (v2f)(0.f);

  W8 wc = loadW(wp);
  __syncthreads();  // xs ready (overlapped with first W load + V load)

  for (int nl = 0; nl < CHUNK; ++nl) {
    // Register double-buffer: prefetch next n's W while computing this one.
    const int nf = (nl + 1 < CHUNK) ? nl + 1 : nl;
    const W8 wn = loadW(wp + (size_t)nf * 128);

    v2f u[BG];
    compute_u(wc, xs, nl, u);

    if (PHASE == 0) {
      // softmax(0) over J is uniform -> plain sum (scale at store).
#pragma unroll
      for (int b = 0; b < BG; ++b) s[b] += u[b];
    } else {
      // logits l[b][j] = sum_d u_hat*V: 2-elem partial per lane, then xor
      // butterfly over the 8 p-lanes.
#pragma unroll
      for (int b = 0; b < BG; ++b) {
        float lp = u[b].x * v0r[b] + u[b].y * v1r[b];
        lp = dpp_add<DPP_QP_XOR1>(lp);
        lp = dpp_add<DPP_QP_XOR2>(lp);
        lp = dpp_add<DPP_HALF_MIRROR>(lp);
        if (p == 0) lmat[b][j] = lp;
      }
      __syncthreads();
      // softmax over j (32 entries) x 8 b; 256 threads handle 1 entry each.
      // |logit| <= ~3: exp safe without max subtraction (validated R2/R4).
      {
        const int jj = tid & 31;
        const int bb = tid >> 5;
        float e0 = __expf(lmat[bb][jj]);
        float m0 = e0;
        m0 = dpp_add<DPP_QP_XOR1>(m0);
        m0 = dpp_add<DPP_QP_XOR2>(m0);
        m0 = dpp_add<DPP_HALF_MIRROR>(m0);
        m0 = dpp_add<DPP_ROR8>(m0);
        m0 += __shfl_xor(m0, 16);
        cmat[bb][jj] = e0 * __builtin_amdgcn_rcpf(m0);
      }
      __syncthreads();
#pragma unroll
      for (int b = 0; b < BG; ++b) {
        const float c = cmat[b][j];  // broadcast (all p-lanes same addr)
        s[b] += u[b] * c;            // one v_pk_fma
      }
      // no 3rd sync needed: next iter writes lmat only after passing the
      // cmat barrier above; all cmat readers finish before that barrier.
    }
    wc = wn;
  }

  const float scale = (PHASE == 0) ? (1.0f / 32.0f) : 1.0f;
#pragma unroll
  for (int b = 0; b < BG; ++b) {
    const size_t off =
        ((size_t)chunk * BB_ + (b0 + b)) * (JJ_ * DD_) + j * DD_ + 2 * p;
    *(float2*)&partial[off] = make_float2(s[b].x * scale, s[b].y * scale);
  }
}

// Reduce over chunks + squash. MODE 0: V = v ; 1: V += v ; 2: out = v.
// 128 blocks x 256 threads, 1 elem/thread; unroll 16 keeps 16 loads in flight.
template <int MODE>
__global__ __launch_bounds__(256) void caps_reduce(
    const float* __restrict__ partial, float* __restrict__ V,
    float* __restrict__ out) {
  const int t = blockIdx.x * 256 + threadIdx.x;  // [0, B*J*D)
  float s = 0.f;
#pragma unroll 16
  for (int c = 0; c < NCHUNKS; ++c)
    s += partial[(size_t)c * (BB_ * JJ_ * DD_) + t];
  // sum of squares over d (16 consecutive lanes = one (b,j))
  float ss = s * s;
  ss += __shfl_xor(ss, 1);
  ss += __shfl_xor(ss, 2);
  ss += __shfl_xor(ss, 4);
  ss += __shfl_xor(ss, 8);
  const float v = s / sqrtf(ss + EPS_);
  if (MODE == 0)
    V[t] = v;
  else if (MODE == 1)
    V[t] += v;
  else
    out[t] = v;
}

extern "C" void kernel_launch(void* const* d_in, const int* in_sizes, int n_in,
                              void* d_out, int out_size, void* d_ws,
                              size_t ws_size, hipStream_t stream) {
  const float* x = (const float*)d_in[0];
  const float* W = (const float*)d_in[1];
  float* out = (float*)d_out;
  float* partial = (float*)d_ws;        // 16.8 MB
  float* V = partial + PARTIAL_FLOATS;  // 128 KB

  const dim3 kgrid(NBG * NCHUNKS);            // 1024 blocks x 256 threads
  const dim3 rgrid((BB_ * JJ_ * DD_) / 256);  // 128 blocks x 256 threads

  caps_phase<0><<<kgrid, 256, 0, stream>>>(x, W, nullptr, partial);
  caps_reduce<0><<<rgrid, 256, 0, stream>>>(partial, V, out);
  caps_phase<1><<<kgrid, 256, 0, stream>>>(x, W, V, partial);
  caps_reduce<1><<<rgrid, 256, 0, stream>>>(partial, V, out);
  caps_phase<2><<<kgrid, 256, 0, stream>>>(x, W, V, partial);
  caps_reduce<2><<<rgrid, 256, 0, stream>>>(partial, V, out);
}